// Round 1
// baseline (242.725 us; speedup 1.0000x reference)
//
#include <hip/hip_runtime.h>

#define MARGIN 0.5f
#define EPS 1e-6f

// One wave (64 lanes) per triplet, grid-stride. Lane i holds float2 at
// element offset 2i -> a whole 512B row per wave-load, fully coalesced.
__global__ __launch_bounds__(256) void triplet_loss_kernel(
    const float* __restrict__ emb,
    const int* __restrict__ aidx,
    const int* __restrict__ pidx,
    const int* __restrict__ nidx,
    float* __restrict__ accum,
    int T)
{
    const int lane = threadIdx.x & 63;
    const int wave_in_blk = threadIdx.x >> 6;
    const int waves_per_blk = blockDim.x >> 6;
    const int gwave = blockIdx.x * waves_per_blk + wave_in_blk;
    const int nwaves = gridDim.x * waves_per_blk;

    float local = 0.f;
    for (int t = gwave; t < T; t += nwaves) {
        const int ai = aidx[t];
        const int pi = pidx[t];
        const int ni = nidx[t];
        const float2* __restrict__ ar = (const float2*)(emb + (size_t)ai * 128);
        const float2* __restrict__ pr = (const float2*)(emb + (size_t)pi * 128);
        const float2* __restrict__ nr = (const float2*)(emb + (size_t)ni * 128);
        float2 a = ar[lane];
        float2 p = pr[lane];
        float2 n = nr[lane];

        float dpx = a.x - p.x + EPS;
        float dpy = a.y - p.y + EPS;
        float dnx = a.x - n.x + EPS;
        float dny = a.y - n.y + EPS;
        float sp = dpx * dpx + dpy * dpy;
        float sn = dnx * dnx + dny * dny;

        // 64-lane butterfly reduction; all lanes end with the full sums
        #pragma unroll
        for (int off = 32; off > 0; off >>= 1) {
            sp += __shfl_xor(sp, off, 64);
            sn += __shfl_xor(sn, off, 64);
        }

        float dpos = sqrtf(sp);
        float dneg = sqrtf(sn);
        local += fmaxf(dpos - dneg + MARGIN, 0.f);
    }

    // block reduction: lane 0 of each wave -> LDS -> thread 0 -> one atomic
    __shared__ float ws_red[8];
    if (lane == 0) ws_red[wave_in_blk] = local;
    __syncthreads();
    if (threadIdx.x == 0) {
        float s = 0.f;
        for (int w = 0; w < waves_per_blk; ++w) s += ws_red[w];
        atomicAdd(accum, s);
    }
}

__global__ void triplet_finalize_kernel(const float* __restrict__ accum,
                                        float* __restrict__ out, float invT)
{
    out[0] = accum[0] * invT;
}

extern "C" void kernel_launch(void* const* d_in, const int* in_sizes, int n_in,
                              void* d_out, int out_size, void* d_ws, size_t ws_size,
                              hipStream_t stream) {
    const float* emb  = (const float*)d_in[0];
    // d_in[1] = labels (unused by the loss computation)
    const int*  aidx  = (const int*)d_in[2];
    const int*  pidx  = (const int*)d_in[3];
    const int*  nidx  = (const int*)d_in[4];
    const int   T     = in_sizes[2];

    float* accum = (float*)d_ws;
    hipMemsetAsync(accum, 0, sizeof(float), stream);

    const int block = 256;                  // 4 waves/block
    const int grid  = 2048;                 // 8192 waves = 32/CU, 32 triplets/wave
    triplet_loss_kernel<<<grid, block, 0, stream>>>(emb, aidx, pidx, nidx, accum, T);
    triplet_finalize_kernel<<<1, 1, 0, stream>>>(accum, (float*)d_out,
                                                 1.0f / (float)T);
}